// Round 3
// baseline (181.797 us; speedup 1.0000x reference)
//
#include <hip/hip_runtime.h>
#include <hip/hip_bf16.h>
#include <stdint.h>

typedef __bf16 bf16_t;
typedef __bf16 bf16x8 __attribute__((ext_vector_type(8)));
typedef float  f32x4  __attribute__((ext_vector_type(4)));

#define DIM    1024
#define NTOK   4096
#define NB     8
#define ROWS   (NB*NTOK)   // 32768
#define QKVC   384
#define INNER  128

// workspace offsets (bytes)
#define OFF_WQ    131072u      // 384*1024 bf16
#define OFF_QKV   1048576u     // 32768*384 bf16
#define OFF_STATS 26214400u    // 512 chunks * 2304 f32
#define OFF_ATTN  30932992u    // 8*8*16*16 f32
#define OFF_WEFF  30998528u    // 8*1024*128 bf16

// ---------- kernel 0: w_qkv * norm_weight -> bf16 ----------
__global__ __launch_bounds__(256) void k_wconv(const float* __restrict__ wq,
    const float* __restrict__ nw, bf16_t* __restrict__ wqb)
{
    int o = blockIdx.x;            // 384 rows
    int c = threadIdx.x * 4;       // 256*4 = 1024
    float4 wv = *reinterpret_cast<const float4*>(wq + (size_t)o*DIM + c);
    float4 nv = *reinterpret_cast<const float4*>(nw + c);
    bf16_t* dst = wqb + (size_t)o*DIM + c;
    dst[0]=(bf16_t)(wv.x*nv.x); dst[1]=(bf16_t)(wv.y*nv.y);
    dst[2]=(bf16_t)(wv.z*nv.z); dst[3]=(bf16_t)(wv.w*nv.w);
}

// ---------- kernel 1: QKV GEMM with fused RMSNorm, reg-staged 2-phase ----------
// (32768x1024)x(1024x384) bf16 MFMA. Pipeline per K-step:
//   convert+ds_write(kt) -> barrier -> issue loads(kt+1) -> ds_read+MFMA(kt) -> barrier
// so the global loads for kt+1 fly under the MFMAs of kt (latency-bound fix; R2
// counters: MfmaUtil 10%, VALUBusy 24%, Occ 16% -> serial-stage latency exposed).
__global__ __launch_bounds__(256, 3) void k_qkv_gemm(const float* __restrict__ x,
    const bf16_t* __restrict__ wq, bf16_t* __restrict__ qkv)
{
    __shared__ bf16_t Al[128*72];   // stride 72 bf16: 2-way-max bank aliasing (free)
    __shared__ bf16_t Bl[128*72];
    __shared__ float srow[128];
    int b0 = blockIdx.x;            // 768 = 256 mt * 3 nt
    int orig = (b0 & 7)*96 + (b0 >> 3);   // contiguous chunk per XCD
    int mt = orig / 3, nt = orig % 3;
    int row0 = mt*128, col0 = nt*128;
    int t = threadIdx.x;
    int w = t >> 6, lane = t & 63, lr = lane & 15, lg = lane >> 4;
    int wr = (w & 1)*64, wc = (w >> 1)*64;
    int r  = t >> 3;                // 0..31 (row within 32-row group)
    int c8 = (t & 7) * 8;           // 0..56 (k offset)

    const float*  xb = x  + (size_t)(row0 + r)*DIM + c8;
    const bf16_t* wb = wq + (size_t)(col0 + r)*DIM + c8;

    float4 a0[4], a1[4];
    uint4  bv[4];
    #pragma unroll
    for (int rd = 0; rd < 4; rd++) {                 // prologue: tile 0
        const float4* xs = reinterpret_cast<const float4*>(xb + (size_t)(32*rd)*DIM);
        a0[rd] = xs[0]; a1[rd] = xs[1];
        bv[rd] = *reinterpret_cast<const uint4*>(wb + (size_t)(32*rd)*DIM);
    }

    float ssq[4] = {0.f, 0.f, 0.f, 0.f};
    f32x4 acc[4][4] = {};

    for (int kt = 0; kt < 16; kt++) {
        // phase 1: convert + ds_write current tile (vmcnt wait folds in here)
        #pragma unroll
        for (int rd = 0; rd < 4; rd++) {
            float4 u0 = a0[rd], u1 = a1[rd];
            ssq[rd] += u0.x*u0.x + u0.y*u0.y + u0.z*u0.z + u0.w*u0.w
                     + u1.x*u1.x + u1.y*u1.y + u1.z*u1.z + u1.w*u1.w;
            bf16x8 v;
            v[0]=(bf16_t)u0.x; v[1]=(bf16_t)u0.y; v[2]=(bf16_t)u0.z; v[3]=(bf16_t)u0.w;
            v[4]=(bf16_t)u1.x; v[5]=(bf16_t)u1.y; v[6]=(bf16_t)u1.z; v[7]=(bf16_t)u1.w;
            *reinterpret_cast<bf16x8*>(&Al[(r + 32*rd)*72 + c8]) = v;
            *reinterpret_cast<uint4*>(&Bl[(r + 32*rd)*72 + c8]) = bv[rd];
        }
        __syncthreads();
        // phase 2: issue next-tile loads (no wait) — fly under the MFMAs below
        if (kt < 15) {
            #pragma unroll
            for (int rd = 0; rd < 4; rd++) {
                const float4* xs = reinterpret_cast<const float4*>(
                    xb + (size_t)(32*rd)*DIM + (kt+1)*64);
                a0[rd] = xs[0]; a1[rd] = xs[1];
                bv[rd] = *reinterpret_cast<const uint4*>(
                    wb + (size_t)(32*rd)*DIM + (kt+1)*64);
            }
        }
        // phase 3: compute on LDS tile kt
        #pragma unroll
        for (int kk = 0; kk < 2; kk++) {
            int kb = kk*32 + lg*8;
            bf16x8 af[4], bfr[4];
            #pragma unroll
            for (int mi = 0; mi < 4; mi++)
                af[mi] = *reinterpret_cast<const bf16x8*>(&Al[(wr + mi*16 + lr)*72 + kb]);
            #pragma unroll
            for (int ni = 0; ni < 4; ni++)
                bfr[ni] = *reinterpret_cast<const bf16x8*>(&Bl[(wc + ni*16 + lr)*72 + kb]);
            #pragma unroll
            for (int mi = 0; mi < 4; mi++)
                #pragma unroll
                for (int ni = 0; ni < 4; ni++)
                    acc[mi][ni] = __builtin_amdgcn_mfma_f32_16x16x32_bf16(
                        af[mi], bfr[ni], acc[mi][ni], 0, 0, 0);
        }
        __syncthreads();
    }
    // per-row sumsq: 8 consecutive lanes share a row -> shuffle reduce
    #pragma unroll
    for (int rd = 0; rd < 4; rd++) {
        float s = ssq[rd];
        s += __shfl_xor(s, 1, 64);
        s += __shfl_xor(s, 2, 64);
        s += __shfl_xor(s, 4, 64);
        if ((t & 7) == 0) srow[r + 32*rd] = rsqrtf(s*(1.0f/DIM) + 1e-6f);
    }
    __syncthreads();
    #pragma unroll
    for (int mi = 0; mi < 4; mi++)
        #pragma unroll
        for (int ni = 0; ni < 4; ni++) {
            int col_g = col0 + wc + ni*16 + lr;
            #pragma unroll
            for (int rr = 0; rr < 4; rr++) {
                int rloc = wr + mi*16 + lg*4 + rr;
                qkv[(size_t)(row0 + rloc)*QKVC + col_g] =
                    (bf16_t)(acc[mi][ni][rr] * srow[rloc]);
            }
        }
}

// ---------- kernel 2: per-(b,chunk) Gram + sumsq partials ----------
__global__ __launch_bounds__(256) void k_stats(const bf16_t* __restrict__ qkv,
    float* __restrict__ stats)
{
    __shared__ bf16_t qk[64*264];   // 64 tokens x 256 (q,k cols) + pad 8
    int bid = blockIdx.x;           // 512 = 8b * 64ch
    int b = bid >> 6, ch = bid & 63;
    int t = threadIdx.x;
    #pragma unroll
    for (int rd = 0; rd < 8; rd++) {
        int tok = (t >> 5) + 8*rd;
        int c8  = (t & 31) * 8;     // cols 0..255 = q,k
        *reinterpret_cast<uint4*>(&qk[tok*264 + c8]) =
            *reinterpret_cast<const uint4*>(
                qkv + ((size_t)b*NTOK + ch*64 + tok)*QKVC + c8);
    }
    __syncthreads();
    int h = t >> 5, s = t & 31, i0 = (s >> 4)*8, j = s & 15;
    float gram[8] = {}, qsq[8] = {}, ksq = 0.f;
    for (int tok = 0; tok < 64; tok++) {
        bf16x8 q8 = *reinterpret_cast<const bf16x8*>(&qk[tok*264 + h*16 + i0]);
        float kf = (float)qk[tok*264 + 128 + h*16 + j];
        ksq += kf*kf;
        #pragma unroll
        for (int m = 0; m < 8; m++) {
            float qf = (float)q8[m];
            gram[m] += qf*kf;
            qsq[m]  += qf*qf;
        }
    }
    float* base = stats + ((size_t)(b*64 + ch)*8 + h)*288;
    #pragma unroll
    for (int m = 0; m < 8; m++) base[(i0 + m)*16 + j] = gram[m];
    if (j == 0) {
        #pragma unroll
        for (int m = 0; m < 8; m++) base[256 + i0 + m] = qsq[m];
    }
    if (s < 16) base[272 + j] = ksq;
}

// ---------- kernel 3: reduce partials, l2-normalize, temperature, softmax ----------
__global__ __launch_bounds__(256) void k_attn(const float* __restrict__ stats,
    const float* __restrict__ temp, float* __restrict__ attn)
{
    int bid = blockIdx.x;           // 64 = 8b * 8h
    int b = bid >> 3, h = bid & 7;
    int t = threadIdx.x, i = t >> 4, j = t & 15;
    float gsum = 0.f, qs = 0.f, ks = 0.f;
    for (int ch = 0; ch < 64; ch++) {
        const float* base = stats + ((size_t)(b*64 + ch)*8 + h)*288;
        gsum += base[i*16 + j];
        qs   += base[256 + i];
        ks   += base[272 + j];
    }
    float et  = expf(temp[h]);
    float sim = gsum * et / (fmaxf(sqrtf(qs), 1e-12f) * fmaxf(sqrtf(ks), 1e-12f));
    float m = sim;
    #pragma unroll
    for (int d = 1; d < 16; d <<= 1) m = fmaxf(m, __shfl_xor(m, d, 16));
    float e = expf(sim - m);
    float ssum = e;
    #pragma unroll
    for (int d = 1; d < 16; d <<= 1) ssum += __shfl_xor(ssum, d, 16);
    attn[((size_t)(b*8 + h)*16 + i)*16 + j] = e / ssum;
}

// ---------- kernel 4: w_eff[b][o][c] = sum_i w_out[o][h*16+i]*attn[b][h][i][j] ----------
__global__ __launch_bounds__(256) void k_weff(const float* __restrict__ attn,
    const float* __restrict__ wout, bf16_t* __restrict__ weff)
{
    __shared__ float at[2048];
    int bid = blockIdx.x;           // 256 = 8b * 32
    int b = bid >> 5, ob = (bid & 31)*32;
    int t = threadIdx.x;
    #pragma unroll
    for (int r = 0; r < 8; r++) at[t + 256*r] = attn[(size_t)b*2048 + t + 256*r];
    __syncthreads();
    int c = t & 127, h = c >> 4, j = c & 15, oo = (t >> 7)*16;
    #pragma unroll
    for (int m = 0; m < 16; m++) {
        int o = ob + oo + m;
        float acc = 0.f;
        #pragma unroll
        for (int i2 = 0; i2 < 16; i2++)
            acc += wout[(size_t)o*INNER + h*16 + i2] * at[(h*16 + i2)*16 + j];
        weff[((size_t)b*DIM + o)*INNER + c] = (bf16_t)acc;
    }
}

// ---------- kernel 5: output GEMM  per b: (4096x128)x(128x1024), fp32 out ----------
__global__ __launch_bounds__(256) void k_out_gemm(const bf16_t* __restrict__ qkv,
    const bf16_t* __restrict__ weff, float* __restrict__ out)
{
    __shared__ bf16_t Al[128*136];
    __shared__ bf16_t Bl[128*136];
    int bid = blockIdx.x;           // 2048 = 8b * 32mt * 8nt
    int b = bid >> 8, rem = bid & 255;
    int mt = rem >> 3, nt = rem & 7;
    int tok0 = mt*128, o0 = nt*128;
    int t = threadIdx.x;
    #pragma unroll
    for (int rd = 0; rd < 8; rd++) {
        int r  = (t >> 4) + 16*rd;
        int c8 = (t & 15) * 8;
        *reinterpret_cast<uint4*>(&Al[r*136 + c8]) =
            *reinterpret_cast<const uint4*>(
                qkv + ((size_t)b*NTOK + tok0 + r)*QKVC + 256 + c8);   // v cols
        *reinterpret_cast<uint4*>(&Bl[r*136 + c8]) =
            *reinterpret_cast<const uint4*>(
                weff + ((size_t)b*DIM + o0 + r)*INNER + c8);
    }
    __syncthreads();
    int w = t >> 6, lane = t & 63, lr = lane & 15, lg = lane >> 4;
    int wr = (w & 1)*64, wc = (w >> 1)*64;
    f32x4 acc[4][4] = {};
    #pragma unroll
    for (int kk = 0; kk < 4; kk++) {
        int kb = kk*32 + lg*8;
        bf16x8 af[4], bfr[4];
        #pragma unroll
        for (int mi = 0; mi < 4; mi++)
            af[mi] = *reinterpret_cast<const bf16x8*>(&Al[(wr + mi*16 + lr)*136 + kb]);
        #pragma unroll
        for (int ni = 0; ni < 4; ni++)
            bfr[ni] = *reinterpret_cast<const bf16x8*>(&Bl[(wc + ni*16 + lr)*136 + kb]);
        #pragma unroll
        for (int mi = 0; mi < 4; mi++)
            #pragma unroll
            for (int ni = 0; ni < 4; ni++)
                acc[mi][ni] = __builtin_amdgcn_mfma_f32_16x16x32_bf16(
                    af[mi], bfr[ni], acc[mi][ni], 0, 0, 0);
    }
    #pragma unroll
    for (int mi = 0; mi < 4; mi++)
        #pragma unroll
        for (int ni = 0; ni < 4; ni++) {
            int col_g = o0 + wc + ni*16 + lr;
            #pragma unroll
            for (int r = 0; r < 4; r++) {
                int row_g = tok0 + wr + mi*16 + lg*4 + r;
                out[((size_t)b*NTOK + row_g)*DIM + col_g] = acc[mi][ni][r];
            }
        }
}

extern "C" void kernel_launch(void* const* d_in, const int* in_sizes, int n_in,
                              void* d_out, int out_size, void* d_ws, size_t ws_size,
                              hipStream_t stream)
{
    const float* x    = (const float*)d_in[0];   // 8*4096*1024
    const float* nw   = (const float*)d_in[1];   // 1024
    const float* wq   = (const float*)d_in[2];   // 384*1024
    const float* temp = (const float*)d_in[3];   // 8
    const float* wout = (const float*)d_in[4];   // 1024*128
    float* out = (float*)d_out;

    char* ws = (char*)d_ws;
    bf16_t* wqb   = (bf16_t*)(ws + OFF_WQ);
    bf16_t* qkv   = (bf16_t*)(ws + OFF_QKV);
    float*  stats = (float*)(ws + OFF_STATS);
    float*  attn  = (float*)(ws + OFF_ATTN);
    bf16_t* weff  = (bf16_t*)(ws + OFF_WEFF);

    k_wconv    <<<384,  256, 0, stream>>>(wq, nw, wqb);
    k_qkv_gemm <<<768,  256, 0, stream>>>(x, wqb, qkv);
    k_stats    <<<512,  256, 0, stream>>>(qkv, stats);
    k_attn     <<<64,   256, 0, stream>>>(stats, temp, attn);
    k_weff     <<<256,  256, 0, stream>>>(attn, wout, weff);
    k_out_gemm <<<2048, 256, 0, stream>>>(qkv, weff, out);
}

// Round 4
// 180.121 us; speedup vs baseline: 1.0093x; 1.0093x over previous
//
#include <hip/hip_runtime.h>
#include <hip/hip_bf16.h>
#include <stdint.h>

typedef __bf16 bf16_t;
typedef __bf16 bf16x8 __attribute__((ext_vector_type(8)));
typedef float  f32x4  __attribute__((ext_vector_type(4)));

#define DIM    1024
#define NTOK   4096
#define NB     8
#define ROWS   (NB*NTOK)   // 32768
#define QKVC   384
#define INNER  128

// workspace offsets (bytes)
#define OFF_WQ    131072u      // 384*1024 bf16
#define OFF_QKV   1048576u     // 32768*384 bf16
#define OFF_STATS 26214400u    // 512 chunks * 2304 f32
#define OFF_ATTN  30932992u    // 8*8*16*16 f32
#define OFF_WEFF  30998528u    // 8*1024*128 bf16

// ---------- kernel 0: w_qkv * norm_weight -> bf16 ----------
__global__ __launch_bounds__(256) void k_wconv(const float* __restrict__ wq,
    const float* __restrict__ nw, bf16_t* __restrict__ wqb)
{
    int o = blockIdx.x;            // 384 rows
    int c = threadIdx.x * 4;       // 256*4 = 1024
    float4 wv = *reinterpret_cast<const float4*>(wq + (size_t)o*DIM + c);
    float4 nv = *reinterpret_cast<const float4*>(nw + c);
    bf16_t* dst = wqb + (size_t)o*DIM + c;
    dst[0]=(bf16_t)(wv.x*nv.x); dst[1]=(bf16_t)(wv.y*nv.y);
    dst[2]=(bf16_t)(wv.z*nv.z); dst[3]=(bf16_t)(wv.w*nv.w);
}

// ---------- kernel 1: QKV GEMM with fused RMSNorm, reg-staged 2-phase ----------
// R3 lesson: __launch_bounds__(256,3) forced the allocator to spill the 48
// staging regs to scratch (WRITE_SIZE 24->148 MB). No min-wave floor here:
// pipeline hides latency via ILP, 2 blocks/CU is enough.
__global__ __launch_bounds__(256) void k_qkv_gemm(const float* __restrict__ x,
    const bf16_t* __restrict__ wq, bf16_t* __restrict__ qkv)
{
    __shared__ bf16_t Al[128*72];   // stride 72 bf16: worst 2-way bank aliasing (free)
    __shared__ bf16_t Bl[128*72];
    __shared__ float srow[128];
    int b0 = blockIdx.x;            // 768 = 256 mt * 3 nt
    int orig = (b0 & 7)*96 + (b0 >> 3);   // contiguous chunk per XCD
    int mt = orig / 3, nt = orig % 3;
    int row0 = mt*128, col0 = nt*128;
    int t = threadIdx.x;
    int w = t >> 6, lane = t & 63, lr = lane & 15, lg = lane >> 4;
    int wr = (w & 1)*64, wc = (w >> 1)*64;
    int r  = t >> 3;                // 0..31 (row within 32-row group)
    int c8 = (t & 7) * 8;           // 0..56 (k offset)

    const float*  xb = x  + (size_t)(row0 + r)*DIM + c8;
    const bf16_t* wb = wq + (size_t)(col0 + r)*DIM + c8;

    float4 a0[4], a1[4];
    uint4  bv[4];
    #pragma unroll
    for (int rd = 0; rd < 4; rd++) {                 // prologue: tile 0
        const float4* xs = reinterpret_cast<const float4*>(xb + (size_t)(32*rd)*DIM);
        a0[rd] = xs[0]; a1[rd] = xs[1];
        bv[rd] = *reinterpret_cast<const uint4*>(wb + (size_t)(32*rd)*DIM);
    }

    float ssq[4] = {0.f, 0.f, 0.f, 0.f};
    f32x4 acc[4][4] = {};

    for (int kt = 0; kt < 16; kt++) {
        // phase 1: convert + ds_write current tile
        #pragma unroll
        for (int rd = 0; rd < 4; rd++) {
            float4 u0 = a0[rd], u1 = a1[rd];
            ssq[rd] += u0.x*u0.x + u0.y*u0.y + u0.z*u0.z + u0.w*u0.w
                     + u1.x*u1.x + u1.y*u1.y + u1.z*u1.z + u1.w*u1.w;
            bf16x8 v;
            v[0]=(bf16_t)u0.x; v[1]=(bf16_t)u0.y; v[2]=(bf16_t)u0.z; v[3]=(bf16_t)u0.w;
            v[4]=(bf16_t)u1.x; v[5]=(bf16_t)u1.y; v[6]=(bf16_t)u1.z; v[7]=(bf16_t)u1.w;
            *reinterpret_cast<bf16x8*>(&Al[(r + 32*rd)*72 + c8]) = v;
            *reinterpret_cast<uint4*>(&Bl[(r + 32*rd)*72 + c8]) = bv[rd];
        }
        __syncthreads();
        // phase 2: issue next-tile loads (no wait) — fly under the MFMAs below
        if (kt < 15) {
            #pragma unroll
            for (int rd = 0; rd < 4; rd++) {
                const float4* xs = reinterpret_cast<const float4*>(
                    xb + (size_t)(32*rd)*DIM + (kt+1)*64);
                a0[rd] = xs[0]; a1[rd] = xs[1];
                bv[rd] = *reinterpret_cast<const uint4*>(
                    wb + (size_t)(32*rd)*DIM + (kt+1)*64);
            }
        }
        // phase 3: compute on LDS tile kt
        #pragma unroll
        for (int kk = 0; kk < 2; kk++) {
            int kb = kk*32 + lg*8;
            bf16x8 af[4], bfr[4];
            #pragma unroll
            for (int mi = 0; mi < 4; mi++)
                af[mi] = *reinterpret_cast<const bf16x8*>(&Al[(wr + mi*16 + lr)*72 + kb]);
            #pragma unroll
            for (int ni = 0; ni < 4; ni++)
                bfr[ni] = *reinterpret_cast<const bf16x8*>(&Bl[(wc + ni*16 + lr)*72 + kb]);
            #pragma unroll
            for (int mi = 0; mi < 4; mi++)
                #pragma unroll
                for (int ni = 0; ni < 4; ni++)
                    acc[mi][ni] = __builtin_amdgcn_mfma_f32_16x16x32_bf16(
                        af[mi], bfr[ni], acc[mi][ni], 0, 0, 0);
        }
        __syncthreads();
    }
    // per-row sumsq: 8 consecutive lanes share a row -> shuffle reduce
    #pragma unroll
    for (int rd = 0; rd < 4; rd++) {
        float s = ssq[rd];
        s += __shfl_xor(s, 1, 64);
        s += __shfl_xor(s, 2, 64);
        s += __shfl_xor(s, 4, 64);
        if ((t & 7) == 0) srow[r + 32*rd] = rsqrtf(s*(1.0f/DIM) + 1e-6f);
    }
    __syncthreads();
    #pragma unroll
    for (int mi = 0; mi < 4; mi++)
        #pragma unroll
        for (int ni = 0; ni < 4; ni++) {
            int col_g = col0 + wc + ni*16 + lr;
            #pragma unroll
            for (int rr = 0; rr < 4; rr++) {
                int rloc = wr + mi*16 + lg*4 + rr;
                qkv[(size_t)(row0 + rloc)*QKVC + col_g] =
                    (bf16_t)(acc[mi][ni][rr] * srow[rloc]);
            }
        }
}

// ---------- kernel 2: per-(b,chunk) Gram + sumsq partials ----------
__global__ __launch_bounds__(256) void k_stats(const bf16_t* __restrict__ qkv,
    float* __restrict__ stats)
{
    __shared__ bf16_t qk[64*264];   // 64 tokens x 256 (q,k cols) + pad 8
    int bid = blockIdx.x;           // 512 = 8b * 64ch
    int b = bid >> 6, ch = bid & 63;
    int t = threadIdx.x;
    #pragma unroll
    for (int rd = 0; rd < 8; rd++) {
        int tok = (t >> 5) + 8*rd;
        int c8  = (t & 31) * 8;     // cols 0..255 = q,k
        *reinterpret_cast<uint4*>(&qk[tok*264 + c8]) =
            *reinterpret_cast<const uint4*>(
                qkv + ((size_t)b*NTOK + ch*64 + tok)*QKVC + c8);
    }
    __syncthreads();
    int h = t >> 5, s = t & 31, i0 = (s >> 4)*8, j = s & 15;
    float gram[8] = {}, qsq[8] = {}, ksq = 0.f;
    for (int tok = 0; tok < 64; tok++) {
        bf16x8 q8 = *reinterpret_cast<const bf16x8*>(&qk[tok*264 + h*16 + i0]);
        float kf = (float)qk[tok*264 + 128 + h*16 + j];
        ksq += kf*kf;
        #pragma unroll
        for (int m = 0; m < 8; m++) {
            float qf = (float)q8[m];
            gram[m] += qf*kf;
            qsq[m]  += qf*qf;
        }
    }
    float* base = stats + ((size_t)(b*64 + ch)*8 + h)*288;
    #pragma unroll
    for (int m = 0; m < 8; m++) base[(i0 + m)*16 + j] = gram[m];
    if (j == 0) {
        #pragma unroll
        for (int m = 0; m < 8; m++) base[256 + i0 + m] = qsq[m];
    }
    if (s < 16) base[272 + j] = ksq;
}

// ---------- kernel 3: reduce partials, l2-normalize, temperature, softmax ----------
__global__ __launch_bounds__(256) void k_attn(const float* __restrict__ stats,
    const float* __restrict__ temp, float* __restrict__ attn)
{
    int bid = blockIdx.x;           // 64 = 8b * 8h
    int b = bid >> 3, h = bid & 7;
    int t = threadIdx.x, i = t >> 4, j = t & 15;
    float gsum = 0.f, qs = 0.f, ks = 0.f;
    for (int ch = 0; ch < 64; ch++) {
        const float* base = stats + ((size_t)(b*64 + ch)*8 + h)*288;
        gsum += base[i*16 + j];
        qs   += base[256 + i];
        ks   += base[272 + j];
    }
    float et  = expf(temp[h]);
    float sim = gsum * et / (fmaxf(sqrtf(qs), 1e-12f) * fmaxf(sqrtf(ks), 1e-12f));
    float m = sim;
    #pragma unroll
    for (int d = 1; d < 16; d <<= 1) m = fmaxf(m, __shfl_xor(m, d, 16));
    float e = expf(sim - m);
    float ssum = e;
    #pragma unroll
    for (int d = 1; d < 16; d <<= 1) ssum += __shfl_xor(ssum, d, 16);
    attn[((size_t)(b*8 + h)*16 + i)*16 + j] = e / ssum;
}

// ---------- kernel 4: w_eff[b][o][c] = sum_i w_out[o][h*16+i]*attn[b][h][i][j] ----------
__global__ __launch_bounds__(256) void k_weff(const float* __restrict__ attn,
    const float* __restrict__ wout, bf16_t* __restrict__ weff)
{
    __shared__ float at[2048];
    int bid = blockIdx.x;           // 256 = 8b * 32
    int b = bid >> 5, ob = (bid & 31)*32;
    int t = threadIdx.x;
    #pragma unroll
    for (int r = 0; r < 8; r++) at[t + 256*r] = attn[(size_t)b*2048 + t + 256*r];
    __syncthreads();
    int c = t & 127, h = c >> 4, j = c & 15, oo = (t >> 7)*16;
    #pragma unroll
    for (int m = 0; m < 16; m++) {
        int o = ob + oo + m;
        float acc = 0.f;
        #pragma unroll
        for (int i2 = 0; i2 < 16; i2++)
            acc += wout[(size_t)o*INNER + h*16 + i2] * at[(h*16 + i2)*16 + j];
        weff[((size_t)b*DIM + o)*INNER + c] = (bf16_t)acc;
    }
}

// ---------- kernel 5: output GEMM  per b: (4096x128)x(128x1024), fp32 out ----------
__global__ __launch_bounds__(256) void k_out_gemm(const bf16_t* __restrict__ qkv,
    const bf16_t* __restrict__ weff, float* __restrict__ out)
{
    __shared__ bf16_t Al[128*136];
    __shared__ bf16_t Bl[128*136];
    int bid = blockIdx.x;           // 2048 = 8b * 32mt * 8nt
    int b = bid >> 8, rem = bid & 255;
    int mt = rem >> 3, nt = rem & 7;
    int tok0 = mt*128, o0 = nt*128;
    int t = threadIdx.x;
    #pragma unroll
    for (int rd = 0; rd < 8; rd++) {
        int r  = (t >> 4) + 16*rd;
        int c8 = (t & 15) * 8;
        *reinterpret_cast<uint4*>(&Al[r*136 + c8]) =
            *reinterpret_cast<const uint4*>(
                qkv + ((size_t)b*NTOK + tok0 + r)*QKVC + 256 + c8);   // v cols
        *reinterpret_cast<uint4*>(&Bl[r*136 + c8]) =
            *reinterpret_cast<const uint4*>(
                weff + ((size_t)b*DIM + o0 + r)*INNER + c8);
    }
    __syncthreads();
    int w = t >> 6, lane = t & 63, lr = lane & 15, lg = lane >> 4;
    int wr = (w & 1)*64, wc = (w >> 1)*64;
    f32x4 acc[4][4] = {};
    #pragma unroll
    for (int kk = 0; kk < 4; kk++) {
        int kb = kk*32 + lg*8;
        bf16x8 af[4], bfr[4];
        #pragma unroll
        for (int mi = 0; mi < 4; mi++)
            af[mi] = *reinterpret_cast<const bf16x8*>(&Al[(wr + mi*16 + lr)*136 + kb]);
        #pragma unroll
        for (int ni = 0; ni < 4; ni++)
            bfr[ni] = *reinterpret_cast<const bf16x8*>(&Bl[(wc + ni*16 + lr)*136 + kb]);
        #pragma unroll
        for (int mi = 0; mi < 4; mi++)
            #pragma unroll
            for (int ni = 0; ni < 4; ni++)
                acc[mi][ni] = __builtin_amdgcn_mfma_f32_16x16x32_bf16(
                    af[mi], bfr[ni], acc[mi][ni], 0, 0, 0);
    }
    #pragma unroll
    for (int mi = 0; mi < 4; mi++)
        #pragma unroll
        for (int ni = 0; ni < 4; ni++) {
            int col_g = o0 + wc + ni*16 + lr;
            #pragma unroll
            for (int r = 0; r < 4; r++) {
                int row_g = tok0 + wr + mi*16 + lg*4 + r;
                out[((size_t)b*NTOK + row_g)*DIM + col_g] = acc[mi][ni][r];
            }
        }
}

extern "C" void kernel_launch(void* const* d_in, const int* in_sizes, int n_in,
                              void* d_out, int out_size, void* d_ws, size_t ws_size,
                              hipStream_t stream)
{
    const float* x    = (const float*)d_in[0];   // 8*4096*1024
    const float* nw   = (const float*)d_in[1];   // 1024
    const float* wq   = (const float*)d_in[2];   // 384*1024
    const float* temp = (const float*)d_in[3];   // 8
    const float* wout = (const float*)d_in[4];   // 1024*128
    float* out = (float*)d_out;

    char* ws = (char*)d_ws;
    bf16_t* wqb   = (bf16_t*)(ws + OFF_WQ);
    bf16_t* qkv   = (bf16_t*)(ws + OFF_QKV);
    float*  stats = (float*)(ws + OFF_STATS);
    float*  attn  = (float*)(ws + OFF_ATTN);
    bf16_t* weff  = (bf16_t*)(ws + OFF_WEFF);

    k_wconv    <<<384,  256, 0, stream>>>(wq, nw, wqb);
    k_qkv_gemm <<<768,  256, 0, stream>>>(x, wqb, qkv);
    k_stats    <<<512,  256, 0, stream>>>(qkv, stats);
    k_attn     <<<64,   256, 0, stream>>>(stats, temp, attn);
    k_weff     <<<256,  256, 0, stream>>>(attn, wout, weff);
    k_out_gemm <<<2048, 256, 0, stream>>>(qkv, weff, out);
}

// Round 6
// 140.463 us; speedup vs baseline: 1.2943x; 1.2823x over previous
//
#include <hip/hip_runtime.h>
#include <hip/hip_bf16.h>
#include <stdint.h>

typedef __bf16 bf16_t;
typedef __bf16 bf16x4 __attribute__((ext_vector_type(4)));
typedef __bf16 bf16x8 __attribute__((ext_vector_type(8)));
typedef float  f32x4  __attribute__((ext_vector_type(4)));

#define DIM    1024
#define NTOK   4096
#define NB     8
#define ROWS   (NB*NTOK)   // 32768
#define QKVC   384
#define INNER  128

// global -> LDS direct copy, 16B per lane (dest = wave-uniform base + lane*16)
#define GLD16(g, l) __builtin_amdgcn_global_load_lds( \
    (const __attribute__((address_space(1))) void*)(g), \
    (__attribute__((address_space(3))) void*)(l), 16, 0, 0)

// workspace offsets (bytes)
#define OFF_WQ    131072u      // 384*1024 bf16   (768 KB)
#define OFF_XB    1048576u     // 32768*1024 bf16 (64 MB)
#define OFF_QKV   68157440u    // 32768*384 bf16  (24 MB)
#define OFF_STATS 93323264u    // 512 chunks * 2304 f32
#define OFF_ATTN  98041856u    // 8*8*16*16 f32
#define OFF_WEFF  98107392u    // 8*1024*128 bf16

// ---------- kernel 0: w_qkv * norm_weight -> bf16 ----------
__global__ __launch_bounds__(256) void k_wconv(const float* __restrict__ wq,
    const float* __restrict__ nw, bf16_t* __restrict__ wqb)
{
    int o = blockIdx.x;            // 384 rows
    int c = threadIdx.x * 4;       // 256*4 = 1024
    float4 wv = *reinterpret_cast<const float4*>(wq + (size_t)o*DIM + c);
    float4 nv = *reinterpret_cast<const float4*>(nw + c);
    bf16_t* dst = wqb + (size_t)o*DIM + c;
    dst[0]=(bf16_t)(wv.x*nv.x); dst[1]=(bf16_t)(wv.y*nv.y);
    dst[2]=(bf16_t)(wv.z*nv.z); dst[3]=(bf16_t)(wv.w*nv.w);
}

// ---------- kernel 1: RMSNorm fold + fp32->bf16: xb = bf16(x * rsqrt(mean+eps)) ----------
__global__ __launch_bounds__(256) void k_prep(const float* __restrict__ x,
    bf16_t* __restrict__ xb)
{
    int row  = blockIdx.x*4 + (threadIdx.x >> 6);
    int lane = threadIdx.x & 63;
    const float4* xv = reinterpret_cast<const float4*>(x + (size_t)row*DIM);
    float4 u[4];
    float ss = 0.f;
    #pragma unroll
    for (int i = 0; i < 4; i++) {
        u[i] = xv[lane + 64*i];
        ss += u[i].x*u[i].x + u[i].y*u[i].y + u[i].z*u[i].z + u[i].w*u[i].w;
    }
    #pragma unroll
    for (int d = 1; d < 64; d <<= 1) ss += __shfl_xor(ss, d, 64);
    float s = rsqrtf(ss*(1.0f/DIM) + 1e-6f);
    bf16_t* dst = xb + (size_t)row*DIM;
    #pragma unroll
    for (int i = 0; i < 4; i++) {
        bf16x4 v;
        v[0]=(bf16_t)(u[i].x*s); v[1]=(bf16_t)(u[i].y*s);
        v[2]=(bf16_t)(u[i].z*s); v[3]=(bf16_t)(u[i].w*s);
        *reinterpret_cast<bf16x4*>(dst + (lane + 64*i)*4) = v;
    }
}

// ---------- kernel 2: QKV GEMM (32768x1024)x(1024x384) bf16 MFMA ----------
// global_load_lds staging, 128x384 tile, 8 waves (2M x 4N), 48 MFMA/wave/K-step.
// LDS linear [row][64]; bank-conflict fix per rule #21: linear LDS dest +
// inverse-swizzled GLOBAL source (k-slot ^= row&7) + swizzled ds_read slot.
// R5 bug fixed: second A-chunk dest is alds+4096 elems (was +32768, OOB).
__global__ __launch_bounds__(512) void k_qkv_gemm(const bf16_t* __restrict__ xb,
    const bf16_t* __restrict__ wqb, bf16_t* __restrict__ qkv)
{
    __shared__ bf16_t Al[128*64];   // 16 KB
    __shared__ bf16_t Bl[384*64];   // 48 KB
    int mt = blockIdx.x;            // 256 blocks = 1/CU
    int row0 = mt*128;
    int t = threadIdx.x;
    int lane = t & 63, lr = lane & 15, lg = lane >> 4;
    int w = t >> 6, wm = w >> 2, wn = w & 3;   // 2M x 4N wave grid

    int srow = t >> 3;              // 0..63 (staging row within 64-row group)
    int sslot = (t & 7) ^ (srow & 7);          // pre-swizzled k-slot
    int sk8  = sslot * 8;
    const bf16_t* abase = xb  + (size_t)(row0 + srow)*DIM + sk8;
    const bf16_t* bbase = wqb + (size_t)srow*DIM + sk8;
    bf16_t* alds = &Al[(t & ~63) * 8];         // wave-uniform base
    bf16_t* blds = &Bl[(t & ~63) * 8];

    int rsw = lr & 7;               // read-side slot XOR (row&7 == lr&7 for all frag rows)

    f32x4 acc[4][6] = {};

    for (int kt = 0; kt < 16; kt++) {
        int ko = kt*64;
        // stage A: rows 0..63 then 64..127
        GLD16(abase + ko,                   alds);
        GLD16(abase + ko + (size_t)64*DIM,  alds + 4096);
        // stage B: 6 chunks of 64 cols
        #pragma unroll
        for (int c = 0; c < 6; c++)
            GLD16(bbase + ko + (size_t)(64*c)*DIM, blds + c*4096);
        __syncthreads();
        #pragma unroll
        for (int kk = 0; kk < 2; kk++) {
            int kb = ((kk*4 + lg) ^ rsw) * 8;  // physical slot of logical k-block
            bf16x8 af[4], bfr[6];
            #pragma unroll
            for (int mi = 0; mi < 4; mi++)
                af[mi] = *reinterpret_cast<const bf16x8*>(
                    &Al[(wm*64 + mi*16 + lr)*64 + kb]);
            #pragma unroll
            for (int ni = 0; ni < 6; ni++)
                bfr[ni] = *reinterpret_cast<const bf16x8*>(
                    &Bl[(wn*96 + ni*16 + lr)*64 + kb]);
            #pragma unroll
            for (int mi = 0; mi < 4; mi++)
                #pragma unroll
                for (int ni = 0; ni < 6; ni++)
                    acc[mi][ni] = __builtin_amdgcn_mfma_f32_16x16x32_bf16(
                        af[mi], bfr[ni], acc[mi][ni], 0, 0, 0);
        }
        __syncthreads();
    }
    #pragma unroll
    for (int mi = 0; mi < 4; mi++)
        #pragma unroll
        for (int ni = 0; ni < 6; ni++) {
            int col_g = wn*96 + ni*16 + lr;
            #pragma unroll
            for (int rr = 0; rr < 4; rr++) {
                int row_g = row0 + wm*64 + mi*16 + lg*4 + rr;
                qkv[(size_t)row_g*QKVC + col_g] = (bf16_t)acc[mi][ni][rr];
            }
        }
}

// ---------- kernel 3: per-(b,chunk) Gram + sumsq partials ----------
__global__ __launch_bounds__(256) void k_stats(const bf16_t* __restrict__ qkv,
    float* __restrict__ stats)
{
    __shared__ bf16_t qk[64*264];   // 64 tokens x 256 (q,k cols) + pad 8
    int bid = blockIdx.x;           // 512 = 8b * 64ch
    int b = bid >> 6, ch = bid & 63;
    int t = threadIdx.x;
    #pragma unroll
    for (int rd = 0; rd < 8; rd++) {
        int tok = (t >> 5) + 8*rd;
        int c8  = (t & 31) * 8;     // cols 0..255 = q,k
        *reinterpret_cast<uint4*>(&qk[tok*264 + c8]) =
            *reinterpret_cast<const uint4*>(
                qkv + ((size_t)b*NTOK + ch*64 + tok)*QKVC + c8);
    }
    __syncthreads();
    int h = t >> 5, s = t & 31, i0 = (s >> 4)*8, j = s & 15;
    float gram[8] = {}, qsq[8] = {}, ksq = 0.f;
    for (int tok = 0; tok < 64; tok++) {
        bf16x8 q8 = *reinterpret_cast<const bf16x8*>(&qk[tok*264 + h*16 + i0]);
        float kf = (float)qk[tok*264 + 128 + h*16 + j];
        ksq += kf*kf;
        #pragma unroll
        for (int m = 0; m < 8; m++) {
            float qf = (float)q8[m];
            gram[m] += qf*kf;
            qsq[m]  += qf*qf;
        }
    }
    float* base = stats + ((size_t)(b*64 + ch)*8 + h)*288;
    #pragma unroll
    for (int m = 0; m < 8; m++) base[(i0 + m)*16 + j] = gram[m];
    if (j == 0) {
        #pragma unroll
        for (int m = 0; m < 8; m++) base[256 + i0 + m] = qsq[m];
    }
    if (s < 16) base[272 + j] = ksq;
}

// ---------- kernel 4: reduce partials, l2-normalize, temperature, softmax ----------
__global__ __launch_bounds__(256) void k_attn(const float* __restrict__ stats,
    const float* __restrict__ temp, float* __restrict__ attn)
{
    int bid = blockIdx.x;           // 64 = 8b * 8h
    int b = bid >> 3, h = bid & 7;
    int t = threadIdx.x, i = t >> 4, j = t & 15;
    float gsum = 0.f, qs = 0.f, ks = 0.f;
    for (int ch = 0; ch < 64; ch++) {
        const float* base = stats + ((size_t)(b*64 + ch)*8 + h)*288;
        gsum += base[i*16 + j];
        qs   += base[256 + i];
        ks   += base[272 + j];
    }
    float et  = expf(temp[h]);
    float sim = gsum * et / (fmaxf(sqrtf(qs), 1e-12f) * fmaxf(sqrtf(ks), 1e-12f));
    float m = sim;
    #pragma unroll
    for (int d = 1; d < 16; d <<= 1) m = fmaxf(m, __shfl_xor(m, d, 16));
    float e = expf(sim - m);
    float ssum = e;
    #pragma unroll
    for (int d = 1; d < 16; d <<= 1) ssum += __shfl_xor(ssum, d, 16);
    attn[((size_t)(b*8 + h)*16 + i)*16 + j] = e / ssum;
}

// ---------- kernel 5: w_eff[b][o][c] = sum_i w_out[o][h*16+i]*attn[b][h][i][j] ----------
__global__ __launch_bounds__(256) void k_weff(const float* __restrict__ attn,
    const float* __restrict__ wout, bf16_t* __restrict__ weff)
{
    __shared__ float at[2048];
    int bid = blockIdx.x;           // 256 = 8b * 32
    int b = bid >> 5, ob = (bid & 31)*32;
    int t = threadIdx.x;
    #pragma unroll
    for (int r = 0; r < 8; r++) at[t + 256*r] = attn[(size_t)b*2048 + t + 256*r];
    __syncthreads();
    int c = t & 127, h = c >> 4, j = c & 15, oo = (t >> 7)*16;
    #pragma unroll
    for (int m = 0; m < 16; m++) {
        int o = ob + oo + m;
        float acc = 0.f;
        #pragma unroll
        for (int i2 = 0; i2 < 16; i2++)
            acc += wout[(size_t)o*INNER + h*16 + i2] * at[(h*16 + i2)*16 + j];
        weff[((size_t)b*DIM + o)*INNER + c] = (bf16_t)acc;
    }
}

// ---------- kernel 6: output GEMM  per b: (4096x128)x(128x1024), fp32 out ----------
__global__ __launch_bounds__(256) void k_out_gemm(const bf16_t* __restrict__ qkv,
    const bf16_t* __restrict__ weff, float* __restrict__ out)
{
    __shared__ bf16_t Al[128*136];
    __shared__ bf16_t Bl[128*136];
    int bid = blockIdx.x;           // 2048 = 8b * 32mt * 8nt
    int b = bid >> 8, rem = bid & 255;
    int mt = rem >> 3, nt = rem & 7;
    int tok0 = mt*128, o0 = nt*128;
    int t = threadIdx.x;
    #pragma unroll
    for (int rd = 0; rd < 8; rd++) {
        int r  = (t >> 4) + 16*rd;
        int c8 = (t & 15) * 8;
        *reinterpret_cast<uint4*>(&Al[r*136 + c8]) =
            *reinterpret_cast<const uint4*>(
                qkv + ((size_t)b*NTOK + tok0 + r)*QKVC + 256 + c8);   // v cols
        *reinterpret_cast<uint4*>(&Bl[r*136 + c8]) =
            *reinterpret_cast<const uint4*>(
                weff + ((size_t)b*DIM + o0 + r)*INNER + c8);
    }
    __syncthreads();
    int w = t >> 6, lane = t & 63, lr = lane & 15, lg = lane >> 4;
    int wr = (w & 1)*64, wc = (w >> 1)*64;
    f32x4 acc[4][4] = {};
    #pragma unroll
    for (int kk = 0; kk < 4; kk++) {
        int kb = kk*32 + lg*8;
        bf16x8 af[4], bfr[4];
        #pragma unroll
        for (int mi = 0; mi < 4; mi++)
            af[mi] = *reinterpret_cast<const bf16x8*>(&Al[(wr + mi*16 + lr)*136 + kb]);
        #pragma unroll
        for (int ni = 0; ni < 4; ni++)
            bfr[ni] = *reinterpret_cast<const bf16x8*>(&Bl[(wc + ni*16 + lr)*136 + kb]);
        #pragma unroll
        for (int mi = 0; mi < 4; mi++)
            #pragma unroll
            for (int ni = 0; ni < 4; ni++)
                acc[mi][ni] = __builtin_amdgcn_mfma_f32_16x16x32_bf16(
                    af[mi], bfr[ni], acc[mi][ni], 0, 0, 0);
    }
    #pragma unroll
    for (int mi = 0; mi < 4; mi++)
        #pragma unroll
        for (int ni = 0; ni < 4; ni++) {
            int col_g = o0 + wc + ni*16 + lr;
            #pragma unroll
            for (int r = 0; r < 4; r++) {
                int row_g = tok0 + wr + mi*16 + lg*4 + r;
                out[((size_t)b*NTOK + row_g)*DIM + col_g] = acc[mi][ni][r];
            }
        }
}

extern "C" void kernel_launch(void* const* d_in, const int* in_sizes, int n_in,
                              void* d_out, int out_size, void* d_ws, size_t ws_size,
                              hipStream_t stream)
{
    const float* x    = (const float*)d_in[0];   // 8*4096*1024
    const float* nw   = (const float*)d_in[1];   // 1024
    const float* wq   = (const float*)d_in[2];   // 384*1024
    const float* temp = (const float*)d_in[3];   // 8
    const float* wout = (const float*)d_in[4];   // 1024*128
    float* out = (float*)d_out;

    char* ws = (char*)d_ws;
    bf16_t* wqb   = (bf16_t*)(ws + OFF_WQ);
    bf16_t* xb    = (bf16_t*)(ws + OFF_XB);
    bf16_t* qkv   = (bf16_t*)(ws + OFF_QKV);
    float*  stats = (float*)(ws + OFF_STATS);
    float*  attn  = (float*)(ws + OFF_ATTN);
    bf16_t* weff  = (bf16_t*)(ws + OFF_WEFF);

    k_wconv    <<<384,  256, 0, stream>>>(wq, nw, wqb);
    k_prep     <<<8192, 256, 0, stream>>>(x, xb);
    k_qkv_gemm <<<256,  512, 0, stream>>>(xb, wqb, qkv);
    k_stats    <<<512,  256, 0, stream>>>(qkv, stats);
    k_attn     <<<64,   256, 0, stream>>>(stats, temp, attn);
    k_weff     <<<256,  256, 0, stream>>>(attn, wout, weff);
    k_out_gemm <<<2048, 256, 0, stream>>>(qkv, weff, out);
}

// Round 7
// 133.678 us; speedup vs baseline: 1.3600x; 1.0508x over previous
//
#include <hip/hip_runtime.h>
#include <hip/hip_bf16.h>
#include <stdint.h>

typedef __bf16 bf16_t;
typedef __bf16 bf16x4 __attribute__((ext_vector_type(4)));
typedef __bf16 bf16x8 __attribute__((ext_vector_type(8)));
typedef float  f32x4  __attribute__((ext_vector_type(4)));

#define DIM    1024
#define NTOK   4096
#define NB     8
#define ROWS   (NB*NTOK)   // 32768
#define QKVC   384
#define INNER  128

// global -> LDS direct copy, 16B per lane (dest = wave-uniform base + lane*16)
#define GLD16(g, l) __builtin_amdgcn_global_load_lds( \
    (const __attribute__((address_space(1))) void*)(g), \
    (__attribute__((address_space(3))) void*)(l), 16, 0, 0)

// workspace offsets (bytes)
#define OFF_WQ    131072u      // 384*1024 bf16   (768 KB)
#define OFF_XB    1048576u     // 32768*1024 bf16 (64 MB)
#define OFF_QKV   68157440u    // 32768*384 bf16  (24 MB)
#define OFF_STATS 93323264u    // 512 chunks * 2304 f32
#define OFF_ATTN  98041856u    // 8*8*16*16 f32
#define OFF_WEFF  98107392u    // 8*1024*128 bf16

// ---------- kernel 0: merged  [blocks 0..8191] RMSNorm-fold x->bf16
//                      [blocks 8192..8575] w_qkv*norm_weight->bf16 ----------
__global__ __launch_bounds__(256) void k_prep(const float* __restrict__ x,
    const float* __restrict__ wq, const float* __restrict__ nw,
    bf16_t* __restrict__ xb, bf16_t* __restrict__ wqb)
{
    if (blockIdx.x >= 8192) {               // wconv part
        int o = blockIdx.x - 8192;          // 384 rows
        int c = threadIdx.x * 4;
        float4 wv = *reinterpret_cast<const float4*>(wq + (size_t)o*DIM + c);
        float4 nv = *reinterpret_cast<const float4*>(nw + c);
        bf16_t* dst = wqb + (size_t)o*DIM + c;
        dst[0]=(bf16_t)(wv.x*nv.x); dst[1]=(bf16_t)(wv.y*nv.y);
        dst[2]=(bf16_t)(wv.z*nv.z); dst[3]=(bf16_t)(wv.w*nv.w);
        return;
    }
    int row  = blockIdx.x*4 + (threadIdx.x >> 6);
    int lane = threadIdx.x & 63;
    const float4* xv = reinterpret_cast<const float4*>(x + (size_t)row*DIM);
    float4 u[4];
    float ss = 0.f;
    #pragma unroll
    for (int i = 0; i < 4; i++) {
        u[i] = xv[lane + 64*i];
        ss += u[i].x*u[i].x + u[i].y*u[i].y + u[i].z*u[i].z + u[i].w*u[i].w;
    }
    #pragma unroll
    for (int d = 1; d < 64; d <<= 1) ss += __shfl_xor(ss, d, 64);
    float s = rsqrtf(ss*(1.0f/DIM) + 1e-6f);
    bf16_t* dst = xb + (size_t)row*DIM;
    #pragma unroll
    for (int i = 0; i < 4; i++) {
        bf16x4 v;
        v[0]=(bf16_t)(u[i].x*s); v[1]=(bf16_t)(u[i].y*s);
        v[2]=(bf16_t)(u[i].z*s); v[3]=(bf16_t)(u[i].w*s);
        *reinterpret_cast<bf16x4*>(dst + (lane + 64*i)*4) = v;
    }
}

// ---------- kernel 1: QKV GEMM (32768x1024)x(1024x384) bf16 MFMA ----------
// R6 structure + LDS double-buffer (T3 minimum): issue STAGE(t+1) into buf^1
// BEFORE computing buf; single barrier per K-step. Load latency hides under
// the 48 MFMA/wave compute phase (R6 was single-buffered: drain exposed/step).
__global__ __launch_bounds__(512) void k_qkv_gemm(const bf16_t* __restrict__ xb,
    const bf16_t* __restrict__ wqb, bf16_t* __restrict__ qkv)
{
    __shared__ bf16_t Al[2][128*64];   // 2 x 16 KB
    __shared__ bf16_t Bl[2][384*64];   // 2 x 48 KB
    int mt = blockIdx.x;               // 256 blocks = 1/CU
    int row0 = mt*128;
    int t = threadIdx.x;
    int lane = t & 63, lr = lane & 15, lg = lane >> 4;
    int w = t >> 6, wm = w >> 2, wn = w & 3;   // 2M x 4N wave grid

    int srow = t >> 3;                 // 0..63 staging row
    int sslot = (t & 7) ^ (srow & 7);  // pre-swizzled k-slot (rule #21)
    int sk8  = sslot * 8;
    const bf16_t* abase = xb  + (size_t)(row0 + srow)*DIM + sk8;
    const bf16_t* bbase = wqb + (size_t)srow*DIM + sk8;
    int ldsoff = (t & ~63) * 8;        // wave-uniform dest base (elems)

    int rsw = lr & 7;                  // read-side slot XOR

#define STAGE(buf, kt) do {                                             \
        int _ko = (kt)*64;                                              \
        GLD16(abase + _ko,                  &Al[buf][ldsoff]);          \
        GLD16(abase + _ko + (size_t)64*DIM, &Al[buf][ldsoff + 4096]);   \
        _Pragma("unroll")                                               \
        for (int _c = 0; _c < 6; _c++)                                  \
            GLD16(bbase + _ko + (size_t)(64*_c)*DIM,                    \
                  &Bl[buf][ldsoff + _c*4096]);                          \
    } while (0)

    f32x4 acc[4][6] = {};

    STAGE(0, 0);
    __syncthreads();                   // drain prologue stage

    for (int kt = 0; kt < 16; kt++) {
        int cur = kt & 1;
        if (kt < 15) STAGE(cur ^ 1, kt + 1);   // fly under the MFMAs below
        #pragma unroll
        for (int kk = 0; kk < 2; kk++) {
            int kb = ((kk*4 + lg) ^ rsw) * 8;  // physical slot of logical k-block
            bf16x8 af[4], bfr[6];
            #pragma unroll
            for (int mi = 0; mi < 4; mi++)
                af[mi] = *reinterpret_cast<const bf16x8*>(
                    &Al[cur][(wm*64 + mi*16 + lr)*64 + kb]);
            #pragma unroll
            for (int ni = 0; ni < 6; ni++)
                bfr[ni] = *reinterpret_cast<const bf16x8*>(
                    &Bl[cur][(wn*96 + ni*16 + lr)*64 + kb]);
            #pragma unroll
            for (int mi = 0; mi < 4; mi++)
                #pragma unroll
                for (int ni = 0; ni < 6; ni++)
                    acc[mi][ni] = __builtin_amdgcn_mfma_f32_16x16x32_bf16(
                        af[mi], bfr[ni], acc[mi][ni], 0, 0, 0);
        }
        __syncthreads();               // stage(t+1) drained + reads of cur done
    }
#undef STAGE
    #pragma unroll
    for (int mi = 0; mi < 4; mi++)
        #pragma unroll
        for (int ni = 0; ni < 6; ni++) {
            int col_g = wn*96 + ni*16 + lr;
            #pragma unroll
            for (int rr = 0; rr < 4; rr++) {
                int row_g = row0 + wm*64 + mi*16 + lg*4 + rr;
                qkv[(size_t)row_g*QKVC + col_g] = (bf16_t)acc[mi][ni][rr];
            }
        }
}

// ---------- kernel 2: per-(b,chunk) Gram + sumsq partials ----------
__global__ __launch_bounds__(256) void k_stats(const bf16_t* __restrict__ qkv,
    float* __restrict__ stats)
{
    __shared__ bf16_t qk[64*264];   // 64 tokens x 256 (q,k cols) + pad 8
    int bid = blockIdx.x;           // 512 = 8b * 64ch
    int b = bid >> 6, ch = bid & 63;
    int t = threadIdx.x;
    #pragma unroll
    for (int rd = 0; rd < 8; rd++) {
        int tok = (t >> 5) + 8*rd;
        int c8  = (t & 31) * 8;     // cols 0..255 = q,k
        *reinterpret_cast<uint4*>(&qk[tok*264 + c8]) =
            *reinterpret_cast<const uint4*>(
                qkv + ((size_t)b*NTOK + ch*64 + tok)*QKVC + c8);
    }
    __syncthreads();
    int h = t >> 5, s = t & 31, i0 = (s >> 4)*8, j = s & 15;
    float gram[8] = {}, qsq[8] = {}, ksq = 0.f;
    for (int tok = 0; tok < 64; tok++) {
        bf16x8 q8 = *reinterpret_cast<const bf16x8*>(&qk[tok*264 + h*16 + i0]);
        float kf = (float)qk[tok*264 + 128 + h*16 + j];
        ksq += kf*kf;
        #pragma unroll
        for (int m = 0; m < 8; m++) {
            float qf = (float)q8[m];
            gram[m] += qf*kf;
            qsq[m]  += qf*qf;
        }
    }
    float* base = stats + ((size_t)(b*64 + ch)*8 + h)*288;
    #pragma unroll
    for (int m = 0; m < 8; m++) base[(i0 + m)*16 + j] = gram[m];
    if (j == 0) {
        #pragma unroll
        for (int m = 0; m < 8; m++) base[256 + i0 + m] = qsq[m];
    }
    if (s < 16) base[272 + j] = ksq;
}

// ---------- kernel 3: reduce partials, l2-normalize, temperature, softmax ----------
__global__ __launch_bounds__(256) void k_attn(const float* __restrict__ stats,
    const float* __restrict__ temp, float* __restrict__ attn)
{
    int bid = blockIdx.x;           // 64 = 8b * 8h
    int b = bid >> 3, h = bid & 7;
    int t = threadIdx.x, i = t >> 4, j = t & 15;
    float gsum = 0.f, qs = 0.f, ks = 0.f;
    for (int ch = 0; ch < 64; ch++) {
        const float* base = stats + ((size_t)(b*64 + ch)*8 + h)*288;
        gsum += base[i*16 + j];
        qs   += base[256 + i];
        ks   += base[272 + j];
    }
    float et  = expf(temp[h]);
    float sim = gsum * et / (fmaxf(sqrtf(qs), 1e-12f) * fmaxf(sqrtf(ks), 1e-12f));
    float m = sim;
    #pragma unroll
    for (int d = 1; d < 16; d <<= 1) m = fmaxf(m, __shfl_xor(m, d, 16));
    float e = expf(sim - m);
    float ssum = e;
    #pragma unroll
    for (int d = 1; d < 16; d <<= 1) ssum += __shfl_xor(ssum, d, 16);
    attn[((size_t)(b*8 + h)*16 + i)*16 + j] = e / ssum;
}

// ---------- kernel 4: w_eff[b][o][c] = sum_i w_out[o][h*16+i]*attn[b][h][i][j] ----------
__global__ __launch_bounds__(256) void k_weff(const float* __restrict__ attn,
    const float* __restrict__ wout, bf16_t* __restrict__ weff)
{
    __shared__ float at[2048];
    int bid = blockIdx.x;           // 256 = 8b * 32
    int b = bid >> 5, ob = (bid & 31)*32;
    int t = threadIdx.x;
    #pragma unroll
    for (int r = 0; r < 8; r++) at[t + 256*r] = attn[(size_t)b*2048 + t + 256*r];
    __syncthreads();
    int c = t & 127, h = c >> 4, j = c & 15, oo = (t >> 7)*16;
    #pragma unroll
    for (int m = 0; m < 16; m++) {
        int o = ob + oo + m;
        float acc = 0.f;
        #pragma unroll
        for (int i2 = 0; i2 < 16; i2++)
            acc += wout[(size_t)o*INNER + h*16 + i2] * at[(h*16 + i2)*16 + j];
        weff[((size_t)b*DIM + o)*INNER + c] = (bf16_t)acc;
    }
}

// ---------- kernel 5: output GEMM  per b: (4096x128)x(128x1024), fp32 out ----------
__global__ __launch_bounds__(256) void k_out_gemm(const bf16_t* __restrict__ qkv,
    const bf16_t* __restrict__ weff, float* __restrict__ out)
{
    __shared__ bf16_t Al[128*136];
    __shared__ bf16_t Bl[128*136];
    int bid = blockIdx.x;           // 2048 = 8b * 32mt * 8nt
    int b = bid >> 8, rem = bid & 255;
    int mt = rem >> 3, nt = rem & 7;
    int tok0 = mt*128, o0 = nt*128;
    int t = threadIdx.x;
    #pragma unroll
    for (int rd = 0; rd < 8; rd++) {
        int r  = (t >> 4) + 16*rd;
        int c8 = (t & 15) * 8;
        *reinterpret_cast<uint4*>(&Al[r*136 + c8]) =
            *reinterpret_cast<const uint4*>(
                qkv + ((size_t)b*NTOK + tok0 + r)*QKVC + 256 + c8);   // v cols
        *reinterpret_cast<uint4*>(&Bl[r*136 + c8]) =
            *reinterpret_cast<const uint4*>(
                weff + ((size_t)b*DIM + o0 + r)*INNER + c8);
    }
    __syncthreads();
    int w = t >> 6, lane = t & 63, lr = lane & 15, lg = lane >> 4;
    int wr = (w & 1)*64, wc = (w >> 1)*64;
    f32x4 acc[4][4] = {};
    #pragma unroll
    for (int kk = 0; kk < 4; kk++) {
        int kb = kk*32 + lg*8;
        bf16x8 af[4], bfr[4];
        #pragma unroll
        for (int mi = 0; mi < 4; mi++)
            af[mi] = *reinterpret_cast<const bf16x8*>(&Al[(wr + mi*16 + lr)*136 + kb]);
        #pragma unroll
        for (int ni = 0; ni < 4; ni++)
            bfr[ni] = *reinterpret_cast<const bf16x8*>(&Bl[(wc + ni*16 + lr)*136 + kb]);
        #pragma unroll
        for (int mi = 0; mi < 4; mi++)
            #pragma unroll
            for (int ni = 0; ni < 4; ni++)
                acc[mi][ni] = __builtin_amdgcn_mfma_f32_16x16x32_bf16(
                    af[mi], bfr[ni], acc[mi][ni], 0, 0, 0);
    }
    #pragma unroll
    for (int mi = 0; mi < 4; mi++)
        #pragma unroll
        for (int ni = 0; ni < 4; ni++) {
            int col_g = o0 + wc + ni*16 + lr;
            #pragma unroll
            for (int r = 0; r < 4; r++) {
                int row_g = tok0 + wr + mi*16 + lg*4 + r;
                out[((size_t)b*NTOK + row_g)*DIM + col_g] = acc[mi][ni][r];
            }
        }
}

extern "C" void kernel_launch(void* const* d_in, const int* in_sizes, int n_in,
                              void* d_out, int out_size, void* d_ws, size_t ws_size,
                              hipStream_t stream)
{
    const float* x    = (const float*)d_in[0];   // 8*4096*1024
    const float* nw   = (const float*)d_in[1];   // 1024
    const float* wq   = (const float*)d_in[2];   // 384*1024
    const float* temp = (const float*)d_in[3];   // 8
    const float* wout = (const float*)d_in[4];   // 1024*128
    float* out = (float*)d_out;

    char* ws = (char*)d_ws;
    bf16_t* wqb   = (bf16_t*)(ws + OFF_WQ);
    bf16_t* xb    = (bf16_t*)(ws + OFF_XB);
    bf16_t* qkv   = (bf16_t*)(ws + OFF_QKV);
    float*  stats = (float*)(ws + OFF_STATS);
    float*  attn  = (float*)(ws + OFF_ATTN);
    bf16_t* weff  = (bf16_t*)(ws + OFF_WEFF);

    k_prep     <<<8576, 256, 0, stream>>>(x, wq, nw, xb, wqb);
    k_qkv_gemm <<<256,  512, 0, stream>>>(xb, wqb, qkv);
    k_stats    <<<512,  256, 0, stream>>>(qkv, stats);
    k_attn     <<<64,   256, 0, stream>>>(stats, temp, attn);
    k_weff     <<<256,  256, 0, stream>>>(attn, wout, weff);
    k_out_gemm <<<2048, 256, 0, stream>>>(qkv, weff, out);
}

// Round 8
// 123.362 us; speedup vs baseline: 1.4737x; 1.0836x over previous
//
#include <hip/hip_runtime.h>
#include <hip/hip_bf16.h>
#include <stdint.h>

typedef __bf16 bf16_t;
typedef __bf16 bf16x4 __attribute__((ext_vector_type(4)));
typedef __bf16 bf16x8 __attribute__((ext_vector_type(8)));
typedef float  f32x4  __attribute__((ext_vector_type(4)));

#define DIM    1024
#define NTOK   4096
#define NB     8
#define ROWS   (NB*NTOK)   // 32768
#define QKVC   384
#define INNER  128

// global -> LDS direct copy, 16B per lane (dest = wave-uniform base + lane*16)
#define GLD16(g, l) __builtin_amdgcn_global_load_lds( \
    (const __attribute__((address_space(1))) void*)(g), \
    (__attribute__((address_space(3))) void*)(l), 16, 0, 0)

// workspace offsets (bytes)
#define OFF_WQ    131072u      // 384*1024 bf16   (768 KB)
#define OFF_QKV   1048576u     // 32768*384 bf16  (24 MB)
#define OFF_STATS 26214400u    // 512 chunks * 2304 f32
#define OFF_ATTN  30932992u    // 8*8*16*16 f32
#define OFF_WEFF  30998528u    // 8*1024*128 bf16

// ---------- kernel 0: w_qkv * norm_weight -> bf16 ----------
__global__ __launch_bounds__(256) void k_wconv(const float* __restrict__ wq,
    const float* __restrict__ nw, bf16_t* __restrict__ wqb)
{
    int o = blockIdx.x;            // 384 rows
    int c = threadIdx.x * 4;
    float4 wv = *reinterpret_cast<const float4*>(wq + (size_t)o*DIM + c);
    float4 nv = *reinterpret_cast<const float4*>(nw + c);
    bf16_t* dst = wqb + (size_t)o*DIM + c;
    dst[0]=(bf16_t)(wv.x*nv.x); dst[1]=(bf16_t)(wv.y*nv.y);
    dst[2]=(bf16_t)(wv.z*nv.z); dst[3]=(bf16_t)(wv.w*nv.w);
}

// ---------- kernel 1: FUSED RMSNorm + QKV GEMM ----------
// Reads x fp32 directly (xb eliminated). A path: 16 fp32 regs/thread ->
// convert -> swizzled ds_write (T14 issue-early/write-late); B path:
// global_load_lds as R7. Raw-x sumsq -> srow; scale fp32 acc at epilogue
// (R3/R4-validated numerics). One barrier/K-step, LDS dbuf 128 KB.
// __launch_bounds__(512,2): pin 1 block/CU -> 256-VGPR budget (no spill).
__global__ __launch_bounds__(512, 2) void k_qkv_gemm(const float* __restrict__ x,
    const bf16_t* __restrict__ wqb, bf16_t* __restrict__ qkv)
{
    __shared__ bf16_t Al[2][128*64];   // 2 x 16 KB
    __shared__ bf16_t Bl[2][384*64];   // 2 x 48 KB
    __shared__ float srow[128];
    int mt = blockIdx.x;               // 256 blocks = 1/CU
    int row0 = mt*128;
    int t = threadIdx.x;
    int lane = t & 63, lr = lane & 15, lg = lane >> 4;
    int w = t >> 6, wm = w >> 2, wn = w & 3;   // 2M x 4N wave grid

    // ---- A staging (regs): thread t owns row rA, fp32 elems fo..fo+15 of 64
    int rA = t >> 2;                   // 0..127
    int fo = (t & 3) * 16;
    const float* xrow = x + (size_t)(row0 + rA)*DIM + fo;
    // A LDS write slots (8 bf16 = 16B each): logical s0 = (t&3)*2, s0+1
    int ws0 = ((t & 3)*2)     ^ (rA & 7);
    int ws1 = ((t & 3)*2 + 1) ^ (rA & 7);

    // ---- B staging (global_load_lds), unchanged from R7
    int srB = t >> 3;                  // 0..63
    int sk8 = ((t & 7) ^ (srB & 7)) * 8;
    const bf16_t* bbase = wqb + (size_t)srB*DIM + sk8;
    int ldsoff = (t & ~63) * 8;        // wave-uniform dest base (elems)

    int rsw = lr & 7;                  // read-side slot XOR

    float4 u0, u1, u2, u3;             // 16 fp32 staging regs

#define LOADA(kt) do {                                                   \
        const float4* _xs = reinterpret_cast<const float4*>(xrow + (kt)*64); \
        u0 = _xs[0]; u1 = _xs[1]; u2 = _xs[2]; u3 = _xs[3];              \
    } while (0)

#define STAGEB(buf, kt) do {                                             \
        int _ko = (kt)*64;                                               \
        _Pragma("unroll")                                                \
        for (int _c = 0; _c < 6; _c++)                                   \
            GLD16(bbase + _ko + (size_t)(64*_c)*DIM,                     \
                  &Bl[buf][ldsoff + _c*4096]);                           \
    } while (0)

#define WRITEA(buf) do {                                                 \
        ssq += u0.x*u0.x + u0.y*u0.y + u0.z*u0.z + u0.w*u0.w             \
             + u1.x*u1.x + u1.y*u1.y + u1.z*u1.z + u1.w*u1.w             \
             + u2.x*u2.x + u2.y*u2.y + u2.z*u2.z + u2.w*u2.w             \
             + u3.x*u3.x + u3.y*u3.y + u3.z*u3.z + u3.w*u3.w;            \
        bf16x8 v0, v1;                                                   \
        v0[0]=(bf16_t)u0.x; v0[1]=(bf16_t)u0.y; v0[2]=(bf16_t)u0.z;      \
        v0[3]=(bf16_t)u0.w; v0[4]=(bf16_t)u1.x; v0[5]=(bf16_t)u1.y;      \
        v0[6]=(bf16_t)u1.z; v0[7]=(bf16_t)u1.w;                          \
        v1[0]=(bf16_t)u2.x; v1[1]=(bf16_t)u2.y; v1[2]=(bf16_t)u2.z;      \
        v1[3]=(bf16_t)u2.w; v1[4]=(bf16_t)u3.x; v1[5]=(bf16_t)u3.y;      \
        v1[6]=(bf16_t)u3.z; v1[7]=(bf16_t)u3.w;                          \
        *reinterpret_cast<bf16x8*>(&Al[buf][rA*64 + ws0*8]) = v0;        \
        *reinterpret_cast<bf16x8*>(&Al[buf][rA*64 + ws1*8]) = v1;        \
    } while (0)

    float ssq = 0.f;
    f32x4 acc[4][6] = {};

    // prologue: tile 0
    LOADA(0);
    STAGEB(0, 0);
    WRITEA(0);                         // compiler waits A vmcnt here
    __syncthreads();                   // drains B GLD16 too

    for (int kt = 0; kt < 16; kt++) {
        int cur = kt & 1;
        if (kt < 15) {
            LOADA(kt + 1);             // issue, no wait
            STAGEB(cur ^ 1, kt + 1);   // fly under MFMAs
        }
        #pragma unroll
        for (int kk = 0; kk < 2; kk++) {
            int kb = ((kk*4 + lg) ^ rsw) * 8;
            bf16x8 af[4], bfr[6];
            #pragma unroll
            for (int mi = 0; mi < 4; mi++)
                af[mi] = *reinterpret_cast<const bf16x8*>(
                    &Al[cur][(wm*64 + mi*16 + lr)*64 + kb]);
            #pragma unroll
            for (int ni = 0; ni < 6; ni++)
                bfr[ni] = *reinterpret_cast<const bf16x8*>(
                    &Bl[cur][(wn*96 + ni*16 + lr)*64 + kb]);
            #pragma unroll
            for (int mi = 0; mi < 4; mi++)
                #pragma unroll
                for (int ni = 0; ni < 6; ni++)
                    acc[mi][ni] = __builtin_amdgcn_mfma_f32_16x16x32_bf16(
                        af[mi], bfr[ni], acc[mi][ni], 0, 0, 0);
        }
        if (kt < 15) WRITEA(cur ^ 1);  // A regs landed during MFMA phase
        __syncthreads();
    }
#undef LOADA
#undef STAGEB
#undef WRITEA

    // per-row sumsq: 4 consecutive threads share row rA
    ssq += __shfl_xor(ssq, 1, 64);
    ssq += __shfl_xor(ssq, 2, 64);
    if ((t & 3) == 0) srow[rA] = rsqrtf(ssq*(1.0f/DIM) + 1e-6f);
    __syncthreads();

    #pragma unroll
    for (int mi = 0; mi < 4; mi++)
        #pragma unroll
        for (int ni = 0; ni < 6; ni++) {
            int col_g = wn*96 + ni*16 + lr;
            #pragma unroll
            for (int rr = 0; rr < 4; rr++) {
                int rloc = wm*64 + mi*16 + lg*4 + rr;
                qkv[(size_t)(row0 + rloc)*QKVC + col_g] =
                    (bf16_t)(acc[mi][ni][rr] * srow[rloc]);
            }
        }
}

// ---------- kernel 2: per-(b,chunk) Gram + sumsq partials ----------
__global__ __launch_bounds__(256) void k_stats(const bf16_t* __restrict__ qkv,
    float* __restrict__ stats)
{
    __shared__ bf16_t qk[64*264];   // 64 tokens x 256 (q,k cols) + pad 8
    int bid = blockIdx.x;           // 512 = 8b * 64ch
    int b = bid >> 6, ch = bid & 63;
    int t = threadIdx.x;
    #pragma unroll
    for (int rd = 0; rd < 8; rd++) {
        int tok = (t >> 5) + 8*rd;
        int c8  = (t & 31) * 8;     // cols 0..255 = q,k
        *reinterpret_cast<uint4*>(&qk[tok*264 + c8]) =
            *reinterpret_cast<const uint4*>(
                qkv + ((size_t)b*NTOK + ch*64 + tok)*QKVC + c8);
    }
    __syncthreads();
    int h = t >> 5, s = t & 31, i0 = (s >> 4)*8, j = s & 15;
    float gram[8] = {}, qsq[8] = {}, ksq = 0.f;
    for (int tok = 0; tok < 64; tok++) {
        bf16x8 q8 = *reinterpret_cast<const bf16x8*>(&qk[tok*264 + h*16 + i0]);
        float kf = (float)qk[tok*264 + 128 + h*16 + j];
        ksq += kf*kf;
        #pragma unroll
        for (int m = 0; m < 8; m++) {
            float qf = (float)q8[m];
            gram[m] += qf*kf;
            qsq[m]  += qf*qf;
        }
    }
    float* base = stats + ((size_t)(b*64 + ch)*8 + h)*288;
    #pragma unroll
    for (int m = 0; m < 8; m++) base[(i0 + m)*16 + j] = gram[m];
    if (j == 0) {
        #pragma unroll
        for (int m = 0; m < 8; m++) base[256 + i0 + m] = qsq[m];
    }
    if (s < 16) base[272 + j] = ksq;
}

// ---------- kernel 3: reduce partials, l2-normalize, temperature, softmax ----------
__global__ __launch_bounds__(256) void k_attn(const float* __restrict__ stats,
    const float* __restrict__ temp, float* __restrict__ attn)
{
    int bid = blockIdx.x;           // 64 = 8b * 8h
    int b = bid >> 3, h = bid & 7;
    int t = threadIdx.x, i = t >> 4, j = t & 15;
    float gsum = 0.f, qs = 0.f, ks = 0.f;
    for (int ch = 0; ch < 64; ch++) {
        const float* base = stats + ((size_t)(b*64 + ch)*8 + h)*288;
        gsum += base[i*16 + j];
        qs   += base[256 + i];
        ks   += base[272 + j];
    }
    float et  = expf(temp[h]);
    float sim = gsum * et / (fmaxf(sqrtf(qs), 1e-12f) * fmaxf(sqrtf(ks), 1e-12f));
    float m = sim;
    #pragma unroll
    for (int d = 1; d < 16; d <<= 1) m = fmaxf(m, __shfl_xor(m, d, 16));
    float e = expf(sim - m);
    float ssum = e;
    #pragma unroll
    for (int d = 1; d < 16; d <<= 1) ssum += __shfl_xor(ssum, d, 16);
    attn[((size_t)(b*8 + h)*16 + i)*16 + j] = e / ssum;
}

// ---------- kernel 4: w_eff[b][o][c] = sum_i w_out[o][h*16+i]*attn[b][h][i][j] ----------
__global__ __launch_bounds__(256) void k_weff(const float* __restrict__ attn,
    const float* __restrict__ wout, bf16_t* __restrict__ weff)
{
    __shared__ float at[2048];
    int bid = blockIdx.x;           // 256 = 8b * 32
    int b = bid >> 5, ob = (bid & 31)*32;
    int t = threadIdx.x;
    #pragma unroll
    for (int r = 0; r < 8; r++) at[t + 256*r] = attn[(size_t)b*2048 + t + 256*r];
    __syncthreads();
    int c = t & 127, h = c >> 4, j = c & 15, oo = (t >> 7)*16;
    #pragma unroll
    for (int m = 0; m < 16; m++) {
        int o = ob + oo + m;
        float acc = 0.f;
        #pragma unroll
        for (int i2 = 0; i2 < 16; i2++)
            acc += wout[(size_t)o*INNER + h*16 + i2] * at[(h*16 + i2)*16 + j];
        weff[((size_t)b*DIM + o)*INNER + c] = (bf16_t)acc;
    }
}

// ---------- kernel 5: output GEMM  per b: (4096x128)x(128x1024), fp32 out ----------
__global__ __launch_bounds__(256) void k_out_gemm(const bf16_t* __restrict__ qkv,
    const bf16_t* __restrict__ weff, float* __restrict__ out)
{
    __shared__ bf16_t Al[128*136];
    __shared__ bf16_t Bl[128*136];
    int bid = blockIdx.x;           // 2048 = 8b * 32mt * 8nt
    int b = bid >> 8, rem = bid & 255;
    int mt = rem >> 3, nt = rem & 7;
    int tok0 = mt*128, o0 = nt*128;
    int t = threadIdx.x;
    #pragma unroll
    for (int rd = 0; rd < 8; rd++) {
        int r  = (t >> 4) + 16*rd;
        int c8 = (t & 15) * 8;
        *reinterpret_cast<uint4*>(&Al[r*136 + c8]) =
            *reinterpret_cast<const uint4*>(
                qkv + ((size_t)b*NTOK + tok0 + r)*QKVC + 256 + c8);   // v cols
        *reinterpret_cast<uint4*>(&Bl[r*136 + c8]) =
            *reinterpret_cast<const uint4*>(
                weff + ((size_t)b*DIM + o0 + r)*INNER + c8);
    }
    __syncthreads();
    int w = t >> 6, lane = t & 63, lr = lane & 15, lg = lane >> 4;
    int wr = (w & 1)*64, wc = (w >> 1)*64;
    f32x4 acc[4][4] = {};
    #pragma unroll
    for (int kk = 0; kk < 4; kk++) {
        int kb = kk*32 + lg*8;
        bf16x8 af[4], bfr[4];
        #pragma unroll
        for (int mi = 0; mi < 4; mi++)
            af[mi] = *reinterpret_cast<const bf16x8*>(&Al[(wr + mi*16 + lr)*136 + kb]);
        #pragma unroll
        for (int ni = 0; ni < 4; ni++)
            bfr[ni] = *reinterpret_cast<const bf16x8*>(&Bl[(wc + ni*16 + lr)*136 + kb]);
        #pragma unroll
        for (int mi = 0; mi < 4; mi++)
            #pragma unroll
            for (int ni = 0; ni < 4; ni++)
                acc[mi][ni] = __builtin_amdgcn_mfma_f32_16x16x32_bf16(
                    af[mi], bfr[ni], acc[mi][ni], 0, 0, 0);
    }
    #pragma unroll
    for (int mi = 0; mi < 4; mi++)
        #pragma unroll
        for (int ni = 0; ni < 4; ni++) {
            int col_g = o0 + wc + ni*16 + lr;
            #pragma unroll
            for (int r = 0; r < 4; r++) {
                int row_g = tok0 + wr + mi*16 + lg*4 + r;
                out[((size_t)b*NTOK + row_g)*DIM + col_g] = acc[mi][ni][r];
            }
        }
}

extern "C" void kernel_launch(void* const* d_in, const int* in_sizes, int n_in,
                              void* d_out, int out_size, void* d_ws, size_t ws_size,
                              hipStream_t stream)
{
    const float* x    = (const float*)d_in[0];   // 8*4096*1024
    const float* nw   = (const float*)d_in[1];   // 1024
    const float* wq   = (const float*)d_in[2];   // 384*1024
    const float* temp = (const float*)d_in[3];   // 8
    const float* wout = (const float*)d_in[4];   // 1024*128
    float* out = (float*)d_out;

    char* ws = (char*)d_ws;
    bf16_t* wqb   = (bf16_t*)(ws + OFF_WQ);
    bf16_t* qkv   = (bf16_t*)(ws + OFF_QKV);
    float*  stats = (float*)(ws + OFF_STATS);
    float*  attn  = (float*)(ws + OFF_ATTN);
    bf16_t* weff  = (bf16_t*)(ws + OFF_WEFF);

    k_wconv    <<<384,  256, 0, stream>>>(wq, nw, wqb);
    k_qkv_gemm <<<256,  512, 0, stream>>>(x, wqb, qkv);
    k_stats    <<<512,  256, 0, stream>>>(qkv, stats);
    k_attn     <<<64,   256, 0, stream>>>(stats, temp, attn);
    k_weff     <<<256,  256, 0, stream>>>(attn, wout, weff);
    k_out_gemm <<<2048, 256, 0, stream>>>(qkv, weff, out);
}